// Round 3
// baseline (361.778 us; speedup 1.0000x reference)
//
#include <hip/hip_runtime.h>
#include <math.h>

typedef float v4f __attribute__((ext_vector_type(4)));

#define XS 2048
#define NN 4096
#define ZS 64
#define DD 6208
#define D4 1552              // DD/4 chunks per row
#define Z0 (XS + NN)         // 6144
#define TOPK 16
#define ZTOPK 8
#define EPS_TIE 1e-9f
#define RNDC 0.5f
#define NXUPD 2047           // x rows updated: 0..2046

// d_out offsets (floats): [z_response(64) | final(6208) | neurons(DD*DD) | ages(6208)]
#define OUT_FINAL 64
#define OUT_NEUR  (64 + DD)
#define OUT_AGES  (OUT_NEUR + (size_t)DD * DD)

// Out-scratch: neurons-output rows <2047 are fully rewritten by phase4, so
// phases 1-3 may use them as scratch. rows 0..23: phase3a partials,
// rows 24..31: phase1 mix_x replicas (atomicAdd, zeroed by memset).

// ws offsets (floats)
#define WS_RESP   0
#define WS_INPT   DD
#define WS_MIXX   (2 * DD)
#define WS_MIXZ   (3 * DD)
#define WS_MIXY   (4 * DD)
#define WS_SCAL   (5 * DD)           // 0 Sii,1 SmmX,2 SmiX,3 SmmZ,4 SmiZ,5 SmmY,6 SmiY,7 denomX
#define WS_SELROW (WS_SCAL + 32)     // 24 ints
#define WS_SELC   (WS_SELROW + 24)   // 24 floats: v/a
#define WS_SELW   (WS_SELC + 24)     // 24 floats: (a-1)/a
#define WS_TOTAL  (WS_SELW + 32)

#define XBLKS 256                    // x-part: 8 full rows per block
#define YZBLKS 2080                  // yz-part: 2 full rows per block

__device__ __forceinline__ v4f ld4(const float* p) { return *(const v4f*)p; }
__device__ __forceinline__ void st4(float* p, v4f v) { *(v4f*)p = v; }
__device__ __forceinline__ v4f v4z() { v4f v; v.x = v.y = v.z = v.w = 0.f; return v; }
__device__ __forceinline__ float dot4(v4f a, v4f b) {
  return fmaf(a.x, b.x, fmaf(a.y, b.y, fmaf(a.z, b.z, a.w * b.w)));
}
__device__ __forceinline__ v4f load_inpt(const float* x, const float* yr,
                                         const float* zv, int c) {
  int col = c * 4;   // chunk boundaries never straddle 2048 / 6144
  if (col < XS) return ld4(x + col);
  if (col < Z0) return ld4(yr + (col - XS));
  return ld4(zv + (col - Z0));
}

// ---------------- Phase 1: matvec + copy rows>=2047 + mix_x partials -------
__global__ __launch_bounds__(256) void k_phase1(
    const float* __restrict__ x, const float* __restrict__ yr,
    const float* __restrict__ zv, const float* __restrict__ neurons,
    const float* __restrict__ ages, float* __restrict__ ws,
    float* __restrict__ outn)
{
  const int t = threadIdx.x;
  const int b = blockIdx.x;

  // inpt chunks in registers: 6 full + epilogue (t<16 covers chunks 1536..1551)
  v4f iv[6];
  #pragma unroll
  for (int k = 0; k < 6; ++k) iv[k] = load_inpt(x, yr, zv, t + 256 * k);
  v4f ive = v4z();
  if (t < 16) ive = ld4(zv + 4 * t + (4 * 1536 - Z0));   // cols 6144+4t

  if (b == 0) {
    #pragma unroll
    for (int k = 0; k < 6; ++k) ((v4f*)(ws + WS_INPT))[t + 256 * k] = iv[k];
    if (t < 16) ((v4f*)(ws + WS_INPT))[1536 + t] = ive;
  }

  if (b < XBLKS) {
    // ---- x-part: 8 full-width rows row0..row0+7 ----
    const int row0 = b * 8;
    v4f macc[6];
    #pragma unroll
    for (int k = 0; k < 6; ++k) macc[k] = v4z();
    v4f mace = v4z();
    float dots[8];

    #pragma unroll
    for (int r = 0; r < 8; ++r) {
      const int row = row0 + r;
      const float* rp = neurons + (size_t)row * DD;
      const float age = ages[row];
      const float w = (row < NXUPD) ? (age - 1.f) / age : 0.f;
      v4f av[6];
      #pragma unroll
      for (int k = 0; k < 6; ++k) av[k] = ld4(rp + 4 * (t + 256 * k));
      v4f ae = v4z();
      if (t < 16) ae = ld4(rp + 4 * (1536 + t));
      float d = 0.f;
      #pragma unroll
      for (int k = 0; k < 6; ++k) {
        d += dot4(av[k], iv[k]);
        macc[k] += w * av[k];
      }
      d += dot4(ae, ive);
      mace += w * ae;
      if (row == 2047) {   // only non-updated x-range row: copy to output
        float* op = outn + (size_t)row * DD;
        #pragma unroll
        for (int k = 0; k < 6; ++k) st4(op + 4 * (t + 256 * k), av[k]);
        if (t < 16) st4(op + 4 * (1536 + t), ae);
      }
      dots[r] = d;
    }

    // block-reduce 8 dots -> resp (block owns rows: plain store)
    __shared__ float wred[4][8];
    const int lane = t & 63, wv = t >> 6;
    #pragma unroll
    for (int r = 0; r < 8; ++r) {
      float v = dots[r];
      #pragma unroll
      for (int m = 32; m >= 1; m >>= 1) v += __shfl_xor(v, m);
      if (lane == 0) wred[wv][r] = v;
    }
    __syncthreads();
    if (t < 8)
      ws[WS_RESP + row0 + t] = wred[0][t] + wred[1][t] + wred[2][t] + wred[3][t];

    // mix_x partial -> replica row 24 + (b&7) in out-scratch (atomicAdd)
    float* mrep = outn + (size_t)(24 + (b & 7)) * DD;
    #pragma unroll
    for (int k = 0; k < 6; ++k) {
      const int c = t + 256 * k;
      atomicAdd(mrep + 4 * c + 0, macc[k].x);
      atomicAdd(mrep + 4 * c + 1, macc[k].y);
      atomicAdd(mrep + 4 * c + 2, macc[k].z);
      atomicAdd(mrep + 4 * c + 3, macc[k].w);
    }
    if (t < 16) {
      const int c = 1536 + t;
      atomicAdd(mrep + 4 * c + 0, mace.x);
      atomicAdd(mrep + 4 * c + 1, mace.y);
      atomicAdd(mrep + 4 * c + 2, mace.z);
      atomicAdd(mrep + 4 * c + 3, mace.w);
    }
  } else {
    // ---- yz-part: 2 full-width rows per block ----
    const int row0 = 2048 + 2 * (b - XBLKS);
    const float* rp0 = neurons + (size_t)row0 * DD;
    const float* rp1 = rp0 + DD;
    float* op0 = outn + (size_t)row0 * DD;
    float* op1 = op0 + DD;

    v4f a0[6], a1[6];
    #pragma unroll
    for (int k = 0; k < 6; ++k) a0[k] = ld4(rp0 + 4 * (t + 256 * k));
    #pragma unroll
    for (int k = 0; k < 6; ++k) a1[k] = ld4(rp1 + 4 * (t + 256 * k));
    v4f ae0 = v4z(), ae1 = v4z();
    if (t < 16) { ae0 = ld4(rp0 + 4 * (1536 + t)); ae1 = ld4(rp1 + 4 * (1536 + t)); }

    float d0 = 0.f, d1 = 0.f;
    #pragma unroll
    for (int k = 0; k < 6; ++k) {
      d0 += dot4(a0[k], iv[k]);
      st4(op0 + 4 * (t + 256 * k), a0[k]);
    }
    #pragma unroll
    for (int k = 0; k < 6; ++k) {
      d1 += dot4(a1[k], iv[k]);
      st4(op1 + 4 * (t + 256 * k), a1[k]);
    }
    if (t < 16) {
      d0 += dot4(ae0, ive); d1 += dot4(ae1, ive);
      st4(op0 + 4 * (1536 + t), ae0);
      st4(op1 + 4 * (1536 + t), ae1);
    }

    __shared__ float red[4][2];
    const int lane = t & 63, wv = t >> 6;
    #pragma unroll
    for (int m = 32; m >= 1; m >>= 1) { d0 += __shfl_xor(d0, m); d1 += __shfl_xor(d1, m); }
    if (lane == 0) { red[wv][0] = d0; red[wv][1] = d1; }
    __syncthreads();
    if (t < 2)
      ws[WS_RESP + row0 + t] = red[0][t] + red[1][t] + red[2][t] + red[3][t];
  }
}

// ---------------- Phase 2: top-ks, final, z_response, ages, scalars --------
__global__ __launch_bounds__(1024) void k_phase2(
    const float* __restrict__ ages, float* __restrict__ ws,
    float* __restrict__ out, const float* __restrict__ outn)
{
  const int t = threadIdx.x;
  const int wv = t >> 6, lane = t & 63;
  __shared__ float swv[64];
  __shared__ int   swi[16];
  __shared__ float s_zval[ZTOPK + 1];
  __shared__ int   s_zidx[ZTOPK + 1];
  __shared__ float s_yval[TOPK + 1];
  __shared__ int   s_yidx[TOPK + 1];
  __shared__ float s_denx, s_ty;
  __shared__ float s_z64[ZS];
  __shared__ float s_cv[272];
  __shared__ int   s_ci[272];

  float* resp = ws + WS_RESP;

  // ---- z top-9 (wave 0, lex-max (v,-i) => jax tie-break) ----
  if (t < ZS) s_z64[t] = resp[Z0 + t];
  __syncthreads();
  if (t < 64) {
    float v = s_z64[t];
    for (int j = 0; j <= ZTOPK; ++j) {
      float bv = v; int bi = t;
      #pragma unroll
      for (int m = 1; m < 64; m <<= 1) {
        float ov = __shfl_xor(bv, m);
        int   oi = __shfl_xor(bi, m);
        if (ov > bv || (ov == bv && oi < bi)) { bv = ov; bi = oi; }
      }
      if (t == 0) { s_zval[j] = bv; s_zidx[j] = bi; }
      if (t == bi) v = -INFINITY;
    }
  }

  // ---- x max & all-zero flag ----
  float lm = -INFINITY; int nz = 0;
  for (int i = t; i < XS; i += 1024) { float v = resp[i]; lm = fmaxf(lm, v); nz |= (v != 0.f); }
  #pragma unroll
  for (int m = 1; m < 64; m <<= 1) { lm = fmaxf(lm, __shfl_xor(lm, m)); nz |= __shfl_xor(nz, m); }
  if (lane == 0) { swv[wv] = lm; swi[wv] = nz; }
  __syncthreads();
  if (t == 0) {
    float m2 = -INFINITY; int n2 = 0;
    for (int q = 0; q < 16; ++q) { m2 = fmaxf(m2, swv[q]); n2 |= swi[q]; }
    float tx = n2 ? 0.f : 1.f;
    s_denx = m2 + EPS_TIE * tx * RNDC;
  }

  // ---- y top-17: per-wave register top-17, then single-wave merge ----
  float yvv[4]; int yii[4];
  #pragma unroll
  for (int j = 0; j < 4; ++j) {
    int idx = wv * 256 + j * 64 + lane;
    yvv[j] = resp[XS + idx];
    yii[j] = idx;
  }
  for (int p = 0; p <= TOPK; ++p) {
    float bv = yvv[0]; int bi = yii[0];
    #pragma unroll
    for (int j = 1; j < 4; ++j)
      if (yvv[j] > bv || (yvv[j] == bv && yii[j] < bi)) { bv = yvv[j]; bi = yii[j]; }
    #pragma unroll
    for (int m = 1; m < 64; m <<= 1) {
      float ov = __shfl_xor(bv, m); int oi = __shfl_xor(bi, m);
      if (ov > bv || (ov == bv && oi < bi)) { bv = ov; bi = oi; }
    }
    if (lane == 0) { s_cv[wv * 17 + p] = bv; s_ci[wv * 17 + p] = bi; }
    #pragma unroll
    for (int j = 0; j < 4; ++j) if (yii[j] == bi) yvv[j] = -INFINITY;
  }
  __syncthreads();
  if (wv == 0) {
    float mv[5]; int mi[5];
    #pragma unroll
    for (int q = 0; q < 5; ++q) {
      int e = q * 64 + lane;
      if (e < 272) { mv[q] = s_cv[e]; mi[q] = s_ci[e]; }
      else         { mv[q] = -INFINITY; mi[q] = 0x7fffffff; }
    }
    for (int p = 0; p <= TOPK; ++p) {
      float bv = mv[0]; int bi = mi[0];
      #pragma unroll
      for (int q = 1; q < 5; ++q)
        if (mv[q] > bv || (mv[q] == bv && mi[q] < bi)) { bv = mv[q]; bi = mi[q]; }
      #pragma unroll
      for (int m = 1; m < 64; m <<= 1) {
        float ov = __shfl_xor(bv, m); int oi = __shfl_xor(bi, m);
        if (ov > bv || (ov == bv && oi < bi)) { bv = ov; bi = oi; }
      }
      if (lane == 0) { s_yval[p] = bv; s_yidx[p] = bi; }
      #pragma unroll
      for (int q = 0; q < 5; ++q) if (mi[q] == bi) mv[q] = -INFINITY;
    }
  }
  __syncthreads();
  if (t == 0) {
    float ty = 0.f;
    for (int q = 0; q < TOPK; ++q) if (s_yval[q] == s_yval[TOPK]) ty = 1.f;
    s_ty = ty;
  }
  __syncthreads();

  // ---- final + z_response ----
  const float denx  = s_denx;
  const float zlast = s_zval[ZTOPK];
  const float zden  = s_zval[0] - zlast;
  const float ylast = s_yval[TOPK];
  const float yden  = s_yval[0] - ylast + EPS_TIE * s_ty * RNDC;
  float* fin = out + OUT_FINAL;
  for (int i = t; i < DD; i += 1024) {
    float v = 0.f;
    if (i < XS) v = resp[i] / denx;
    fin[i] = v;
  }
  __syncthreads();
  if (t < ZTOPK)                  fin[Z0 + s_zidx[t]] = (s_zval[t] - zlast) / zden;
  else if (t >= 32 && t < 32 + TOPK) { int k = t - 32; fin[XS + s_yidx[k]] = (s_yval[k] - ylast) / yden; }
  if (t >= 128 && t < 192) {
    int i = t - 128;
    float v = 0.f;
    for (int k = 0; k < ZTOPK; ++k) if (s_zidx[k] == i) v = (s_zval[k] - zlast) / zden;
    out[i] = v;
  }

  // ---- ages ----
  float* oag = out + OUT_AGES;
  for (int i = t; i < DD; i += 1024) oag[i] = ages[i] + ((i < NXUPD) ? 1.f : 0.f);
  __syncthreads();
  if (t < ZTOPK + TOPK) {
    int row = (t < ZTOPK) ? (Z0 + s_zidx[t]) : (XS + s_yidx[t - ZTOPK]);
    oag[row] = ages[row] + 1.f;
  }

  // ---- sum 8 mix_x replicas (out-scratch rows 24..31) -> WS_MIXX ----
  {
    const float* mrep = outn + 24 * (size_t)DD;
    for (int i = t; i < DD; i += 1024) {
      float s = 0.f;
      #pragma unroll
      for (int r = 0; r < 8; ++r) s += mrep[(size_t)r * DD + i];
      ws[WS_MIXX + i] = s;
    }
  }
  __syncthreads();

  // ---- scalars: ||inpt||^2, ||mix_x||^2, mix_x . inpt ----
  float sii = 0.f, smm = 0.f, smi = 0.f;
  float* inpt = ws + WS_INPT;
  float* mixx = ws + WS_MIXX;
  for (int i = t; i < DD; i += 1024) {
    float ip = inpt[i], mx = mixx[i];
    sii = fmaf(ip, ip, sii); smm = fmaf(mx, mx, smm); smi = fmaf(mx, ip, smi);
  }
  #pragma unroll
  for (int m = 1; m < 64; m <<= 1) {
    sii += __shfl_xor(sii, m); smm += __shfl_xor(smm, m); smi += __shfl_xor(smi, m);
  }
  __syncthreads();
  if (lane == 0) { swv[wv] = sii; swv[16 + wv] = smm; swv[32 + wv] = smi; }
  __syncthreads();
  if (t == 0) {
    float a = 0.f, b = 0.f, c = 0.f;
    for (int q = 0; q < 16; ++q) { a += swv[q]; b += swv[16 + q]; c += swv[32 + q]; }
    float* scal = ws + WS_SCAL;
    scal[0] = a; scal[1] = b; scal[2] = c; scal[7] = denx;
  }

  // ---- selected-row tables ----
  if (t < ZTOPK) {
    int row = Z0 + s_zidx[t];
    ((int*)(ws + WS_SELROW))[t] = row;
    float a = ages[row];
    ws[WS_SELC + t] = s_zval[t] / a;
    ws[WS_SELW + t] = (a - 1.f) / a;
  } else if (t >= 32 && t < 32 + TOPK) {
    int k = t - 32;
    int row = XS + s_yidx[k];
    ((int*)(ws + WS_SELROW))[ZTOPK + k] = row;
    float a = ages[row];
    ws[WS_SELC + ZTOPK + k] = s_yval[k] / a;
    ws[WS_SELW + ZTOPK + k] = (a - 1.f) / a;
  }
}

// ---------------- Phase 3a: 24 scaled-row partials into out-scratch --------
__global__ __launch_bounds__(256) void k_phase3a(
    const float* __restrict__ neurons, const float* __restrict__ ws,
    float* __restrict__ outn)
{
  const int b = blockIdx.x;
  const int t = threadIdx.x;
  const int row = ((const int*)(ws + WS_SELROW))[b];
  const float w = ws[WS_SELW + b];
  const float* src = neurons + (size_t)row * DD;
  float* dst = outn + (size_t)b * DD;     // scratch rows 0..23
  #pragma unroll
  for (int k = 0; k < 6; ++k) {
    const int c = t + 256 * k;
    st4(dst + 4 * c, w * ld4(src + 4 * c));
  }
  if (t < 16) {
    const int c = 1536 + t;
    st4(dst + 4 * c, w * ld4(src + 4 * c));
  }
}

// ---------------- Phase 3b: sum partials -> MIXZ/MIXY + scalars ------------
__global__ __launch_bounds__(256) void k_phase3b(
    const float* __restrict__ outn, float* __restrict__ ws)
{
  const int t = threadIdx.x;
  float smmz = 0.f, smiz = 0.f, smmy = 0.f, smiy = 0.f;
  for (int i = blockIdx.x * 256 + t; i < DD; i += 16 * 256) {
    float ip = ws[WS_INPT + i];
    float sz = 0.f, sy = 0.f;
    #pragma unroll
    for (int r = 0; r < 8; ++r)  sz += outn[(size_t)r * DD + i];
    #pragma unroll
    for (int r = 8; r < 24; ++r) sy += outn[(size_t)r * DD + i];
    ws[WS_MIXZ + i] = sz;
    ws[WS_MIXY + i] = sy;
    smmz = fmaf(sz, sz, smmz); smiz = fmaf(sz, ip, smiz);
    smmy = fmaf(sy, sy, smmy); smiy = fmaf(sy, ip, smiy);
  }
  __shared__ float red[4][4];
  const int lane = t & 63, wv = t >> 6;
  #pragma unroll
  for (int m = 32; m >= 1; m >>= 1) {
    smmz += __shfl_xor(smmz, m); smiz += __shfl_xor(smiz, m);
    smmy += __shfl_xor(smmy, m); smiy += __shfl_xor(smiy, m);
  }
  if (lane == 0) { red[wv][0] = smmz; red[wv][1] = smiz; red[wv][2] = smmy; red[wv][3] = smiy; }
  __syncthreads();
  if (t < 4) {
    float s = red[0][t] + red[1][t] + red[2][t] + red[3][t];
    atomicAdd(ws + WS_SCAL + 3 + t, s);   // zeroed by memset
  }
}

// ---------------- Phase 4: write the 2071 updated rows ---------------------
__global__ __launch_bounds__(256) void k_phase4(
    const float* __restrict__ ages, const float* __restrict__ ws,
    float* __restrict__ outn)
{
  const int b = blockIdx.x;
  const int t = threadIdx.x;
  const float sii = ws[WS_SCAL + 0];
  int row; float c, smm, smi; const float* mix;
  if (b < NXUPD) {
    row = b;
    float a = ages[row];
    c = (ws[WS_RESP + row] / ws[WS_SCAL + 7]) / a;   // xvals[row] / age
    mix = ws + WS_MIXX; smm = ws[WS_SCAL + 1]; smi = ws[WS_SCAL + 2];
  } else {
    int k = b - NXUPD;
    row = ((const int*)(ws + WS_SELROW))[k];
    c = ws[WS_SELC + k];
    if (k < ZTOPK) { mix = ws + WS_MIXZ; smm = ws[WS_SCAL + 3]; smi = ws[WS_SCAL + 4]; }
    else           { mix = ws + WS_MIXY; smm = ws[WS_SCAL + 5]; smi = ws[WS_SCAL + 6]; }
  }
  // ||mix + c*inpt||^2 = smm + 2c*smi + c^2*sii
  const float inv = 1.f / (sqrtf(fmaf(c, fmaf(c, sii, 2.f * smi), smm)) + 1e-12f);
  const float* inpt = ws + WS_INPT;
  float* dst = outn + (size_t)row * DD;
  #pragma unroll
  for (int k = 0; k < 6; ++k) {
    const int i = t + 256 * k;
    v4f o = (((const v4f*)mix)[i] + c * ((const v4f*)inpt)[i]) * inv;
    st4(dst + 4 * i, o);
  }
  if (t < 16) {
    const int i = 1536 + t;
    v4f o = (((const v4f*)mix)[i] + c * ((const v4f*)inpt)[i]) * inv;
    st4(dst + 4 * i, o);
  }
}

// ---------------- launcher -------------------------------------------------
extern "C" void kernel_launch(void* const* d_in, const int* in_sizes, int n_in,
                              void* d_out, int out_size, void* d_ws, size_t ws_size,
                              hipStream_t stream)
{
  (void)in_sizes; (void)n_in; (void)out_size; (void)ws_size;
  const float* x    = (const float*)d_in[0];
  const float* zin  = (const float*)d_in[1];   // setup order: x, z, y_response, neurons, ages
  const float* yr   = (const float*)d_in[2];
  const float* neur = (const float*)d_in[3];
  const float* ages = (const float*)d_in[4];
  float* out = (float*)d_out;
  float* ws  = (float*)d_ws;
  float* outn = out + OUT_NEUR;

  hipMemsetAsync(d_ws, 0, (size_t)WS_TOTAL * sizeof(float), stream);
  hipMemsetAsync(outn + 24 * (size_t)DD, 0, 8 * (size_t)DD * sizeof(float), stream);
  k_phase1<<<XBLKS + YZBLKS, 256, 0, stream>>>(x, yr, zin, neur, ages, ws, outn);
  k_phase2<<<1, 1024, 0, stream>>>(ages, ws, out, outn);
  k_phase3a<<<ZTOPK + TOPK, 256, 0, stream>>>(neur, ws, outn);
  k_phase3b<<<16, 256, 0, stream>>>(outn, ws);
  k_phase4<<<NXUPD + ZTOPK + TOPK, 256, 0, stream>>>(ages, ws, outn);
}